// Round 4
// baseline (380.219 us; speedup 1.0000x reference)
//
#include <hip/hip_runtime.h>
#include <hip/hip_bf16.h>
#include <math.h>

// Problem constants
#define Bq  512
#define Lq  41
#define Vq  4
#define Dq  64
#define NLq 3
#define DIq 128
#define Nq  16
#define DTRq 4
#define Kq  4
#define NSq 3
#define H1q 384
#define H2q 16
#define FLATq (Lq*Dq)   // 2624

typedef __attribute__((ext_vector_type(8))) short frag8;   // 8 bf16 (4 VGPRs)
typedef __attribute__((ext_vector_type(4))) float f32x4;

__device__ __forceinline__ float b2f(unsigned short u) {
    union { float f; unsigned int i; } v; v.i = ((unsigned int)u) << 16; return v.f;
}
// round-to-nearest-even (used in prep where cost is amortized)
__device__ __forceinline__ unsigned short f2b_rne(float f) {
    union { float f; unsigned int i; } v; v.f = f;
    unsigned int x = v.i;
    return (unsigned short)((x + 0x7fffu + ((x >> 16) & 1u)) >> 16);
}
// truncation (1 VALU op) — plenty accurate for activations here
__device__ __forceinline__ unsigned short f2b_tr(float f) {
    union { float f; unsigned int i; } v; v.f = f;
    return (unsigned short)(v.i >> 16);
}
__device__ __forceinline__ float fast_rcp(float x) { return __builtin_amdgcn_rcpf(x); }

// ---------------------------------------------------------------------------
// prep: blocks [0,246) transpose W1 -> W1b bf16 [384][2624];
//       blocks [246,1326) convert/transpose small weights.
// ---------------------------------------------------------------------------
__global__ __launch_bounds__(256) void prep_kernel(const float* __restrict__ W1,
                                                   const float* __restrict__ in_proj,
                                                   const float* __restrict__ x_proj,
                                                   const float* __restrict__ out_proj,
                                                   unsigned short* __restrict__ W1b,
                                                   unsigned short* __restrict__ Wb_in,
                                                   unsigned short* __restrict__ xp_b,
                                                   unsigned short* __restrict__ op_b) {
    const int bx = blockIdx.x;
    if (bx < 246) {
        __shared__ float t[64][65];
        const int k0 = (bx / 6) * 64, n0 = (bx % 6) * 64;
        for (int idx = threadIdx.x; idx < 4096; idx += 256) {
            int kr = idx >> 6, nc = idx & 63;
            t[kr][nc] = W1[(size_t)(k0 + kr) * H1q + n0 + nc];
        }
        __syncthreads();
        for (int idx = threadIdx.x; idx < 4096; idx += 256) {
            int nr = idx >> 6, kc = idx & 63;
            W1b[(size_t)(n0 + nr) * FLATq + k0 + kc] = f2b_rne(t[kc][nr]);
        }
        return;
    }
    int idx = (bx - 246) * 256 + threadIdx.x;
    if (idx < 9*256*64) {
        int sl = idx >> 14, rem = idx & 16383;
        int n = rem >> 6, k = rem & 63;
        Wb_in[idx] = f2b_rne(in_proj[(size_t)sl*16384 + k*256 + n]);
    } else if (idx < 9*256*64 + 9*48*128) {
        int i2 = idx - 9*256*64;
        int sl = i2 / 6144, rem = i2 % 6144;
        int c = rem >> 7, k = rem & 127;
        float v = (c < 36) ? x_proj[(size_t)sl*(128*36) + k*36 + c] : 0.f;
        xp_b[i2] = f2b_rne(v);
    } else if (idx < 9*256*64 + 9*48*128 + 9*64*128) {
        int i3 = idx - (9*256*64 + 9*48*128);
        int sl = i3 >> 13, rem = i3 & 8191;
        int n = rem >> 7, k = rem & 127;
        op_b[i3] = f2b_rne(out_proj[(size_t)sl*8192 + k*64 + n]);
    }
}

// ---------------------------------------------------------------------------
// mamba_stack: ALL 3 layers for one (s,b), residual kept in LDS.
// LDS: xt 10496 + u 13056 + rs 10496 + union{xn 6912 | dbl 6560} = 40960 B
//   -> exactly 4 blocks/CU.
// ---------------------------------------------------------------------------
__global__ __launch_bounds__(256, 4) void mamba_stack(
    float* __restrict__ X,                      // [NS][B][L][D] OUTPUT (final residual)
    const int* __restrict__ ids,
    const float* __restrict__ emb,
    const unsigned short* __restrict__ Wb_in,   // [9][256][64]
    const float* __restrict__ conv_w,
    const float* __restrict__ conv_b,
    const unsigned short* __restrict__ xp_b,    // [9][48][128]
    const float* __restrict__ dt_w,
    const float* __restrict__ dt_b,
    const float* __restrict__ A_log,
    const float* __restrict__ Dp,
    const unsigned short* __restrict__ op_b,    // [9][64][128]
    const float* __restrict__ norm_w)
{
    const int b = blockIdx.x, s = blockIdx.y, tid = threadIdx.x;
    const int wave = tid >> 6, lane = tid & 63;
    const int nl = lane & 15, quad = lane >> 4;

    __shared__ float          xt  [Lq][64];     // residual stream (fp32)
    __shared__ unsigned short u_lb[48][136];    // bf16 u; z in place after scan
    __shared__ unsigned short rs_lb[Lq][128];   // bf16 silu(res)
    __shared__ __align__(16) char un_buf[6912]; // union: xn (A->B) | dbl (D->F)
    unsigned short (*xn_lb)[72] = (unsigned short(*)[72])un_buf;
    float          (*dbl_s)[40] = (float(*)[40])un_buf;

    // ---- residual init from embedding (layer 0) --------------------------
    for (int l = wave; l < Lq; l += 4) {
        int id = ids[b * Lq + l];
        xt[l][lane] = emb[id * Dq + lane];      // same (wave,lane) as A reads
    }
    // no barrier needed: A reads xt[l][lane] with identical thread mapping

    for (int layer = 0; layer < NLq; ++layer) {
        const int sl = s * NLq + layer;

        // ---- A: rmsnorm(xt) -> xn bf16; pad rows zeroed ------------------
        {
            const float nwv = norm_w[(size_t)sl * Dq + lane];
            for (int l = wave; l < 48; l += 4) {
                if (l < Lq) {
                    float v  = xt[l][lane];
                    float ss = v * v;
                    #pragma unroll
                    for (int off = 32; off; off >>= 1) ss += __shfl_xor(ss, off, 64);
                    float scale = __builtin_amdgcn_rsqf(ss * (1.0f / Dq) + 1e-5f);
                    xn_lb[l][lane] = f2b_tr(v * scale * nwv);
                } else {
                    xn_lb[l][lane] = 0;
                }
            }
        }
        __syncthreads();

        // ---- B: [48,64]@[64,256] MFMA -> u (cols<128), silu -> rs --------
        {
            #pragma unroll
            for (int t = 0; t < 12; ++t) {
                const int id = wave * 12 + t;
                const int mt = id >> 4, nt = id & 15;
                const unsigned short* Wp = Wb_in + ((size_t)(sl * 256 + nt * 16 + nl)) * 64 + quad * 8;
                frag8 a0 = *(const frag8*)&xn_lb[mt * 16 + nl][quad * 8];
                frag8 a1 = *(const frag8*)&xn_lb[mt * 16 + nl][32 + quad * 8];
                frag8 b0 = *(const frag8*)&Wp[0];
                frag8 b1 = *(const frag8*)&Wp[32];
                f32x4 c = {0.f, 0.f, 0.f, 0.f};
                c = __builtin_amdgcn_mfma_f32_16x16x32_bf16(a0, b0, c, 0, 0, 0);
                c = __builtin_amdgcn_mfma_f32_16x16x32_bf16(a1, b1, c, 0, 0, 0);
                const int col = nt * 16 + nl;
                const int r0 = mt * 16 + quad * 4;
                if (col < DIq) {
                    #pragma unroll
                    for (int r = 0; r < 4; ++r) u_lb[r0 + r][col] = f2b_tr(c[r]);
                } else {
                    const int d = col - DIq;
                    #pragma unroll
                    for (int r = 0; r < 4; ++r) {
                        int row = r0 + r;
                        if (row < Lq) {
                            float v = c[r];
                            rs_lb[row][d] = f2b_tr(v * fast_rcp(1.f + __expf(-v)));
                        }
                    }
                }
            }
        }
        __syncthreads();

        // ---- C: depthwise causal conv (K=4) + bias + silu, in place ------
        {
            const float* cw = conv_w + (size_t)sl * (DIq * Kq);
            const int d = tid >> 1, half = tid & 1;
            const float c0 = cw[d*4+0], c1 = cw[d*4+1], c2 = cw[d*4+2], c3 = cw[d*4+3];
            const float cbv = conv_b[(size_t)sl * DIq + d];
            float w0 = 0.f, w1 = 0.f, w2 = 0.f;
            if (half) { w0 = b2f(u_lb[18][d]); w1 = b2f(u_lb[19][d]); w2 = b2f(u_lb[20][d]); }
            const int base = half ? 21 : 0;
            const int cnt  = half ? 20 : 21;
            for (int i = 0; i < cnt; ++i) {
                int l = base + i;
                float cur = b2f(u_lb[l][d]);
                float a = fmaf(w0, c0, fmaf(w1, c1, fmaf(w2, c2, fmaf(cur, c3, cbv))));
                u_lb[l][d] = f2b_tr(a * fast_rcp(1.f + __expf(-a)));
                w0 = w1; w1 = w2; w2 = cur;
            }
        }
        __syncthreads();

        // ---- D: dbl = u[48,128] @ xp[128,48] MFMA (keep cols<40) ---------
        {
            for (int t = wave; t < 9; t += 4) {
                const int mt = t / 3, ct = t % 3;
                f32x4 c = {0.f, 0.f, 0.f, 0.f};
                #pragma unroll
                for (int kt = 0; kt < 4; ++kt) {
                    frag8 a  = *(const frag8*)&u_lb[mt * 16 + nl][kt * 32 + quad * 8];
                    frag8 bb = *(const frag8*)&xp_b[((size_t)(sl * 48 + ct * 16 + nl)) * 128 + kt * 32 + quad * 8];
                    c = __builtin_amdgcn_mfma_f32_16x16x32_bf16(a, bb, c, 0, 0, 0);
                }
                const int col = ct * 16 + nl, r0 = mt * 16 + quad * 4;
                if (col < 40) {
                    #pragma unroll
                    for (int r = 0; r < 4; ++r) {
                        int row = r0 + r;
                        if (row < Lq) dbl_s[row][col] = c[r];
                    }
                }
            }
        }
        __syncthreads();

        // ---- F: selective scan, fp32 state; z -> u_lb in place -----------
        {
            const int d = tid >> 1, half = tid & 1;
            const float* al = A_log + (size_t)sl * (DIq * Nq) + d * Nq + half * 8;
            float A2[8], h[8];
            #pragma unroll
            for (int n = 0; n < 8; ++n) {
                A2[n] = -__expf(al[n]) * 1.442695041f;   // fold log2(e) into A
                h[n] = 0.f;
            }
            const float* dw = dt_w + (size_t)sl * (DTRq * DIq);
            const float dw0 = dw[d], dw1 = dw[DIq + d], dw2 = dw[2*DIq + d], dw3 = dw[3*DIq + d];
            const float dbv = dt_b[(size_t)sl * DIq + d];
            const float dpd = Dp[(size_t)sl * DIq + d];
            for (int l = 0; l < Lq; ++l) {
                float4 q0 = *(const float4*)&dbl_s[l][0];
                float x  = fmaf(q0.x, dw0, fmaf(q0.y, dw1, fmaf(q0.z, dw2, fmaf(q0.w, dw3, dbv))));
                float dt_ = fmaxf(x, 0.f) + __logf(1.f + __expf(-fabsf(x)));
                float u_  = b2f(u_lb[l][d]);
                float rsv = b2f(rs_lb[l][d]);
                float4 B0 = *(const float4*)&dbl_s[l][4  + half * 8];
                float4 B1 = *(const float4*)&dbl_s[l][8  + half * 8];
                float4 C0 = *(const float4*)&dbl_s[l][20 + half * 8];
                float4 C1 = *(const float4*)&dbl_s[l][24 + half * 8];
                float dtu = dt_ * u_;
                float Bv[8] = {B0.x,B0.y,B0.z,B0.w,B1.x,B1.y,B1.z,B1.w};
                float Cv[8] = {C0.x,C0.y,C0.z,C0.w,C1.x,C1.y,C1.z,C1.w};
                float y = 0.f;
                #pragma unroll
                for (int n = 0; n < 8; ++n) {
                    float dA = __builtin_amdgcn_exp2f(dt_ * A2[n]);
                    h[n] = fmaf(dA, h[n], Bv[n] * dtu);
                    y    = fmaf(h[n], Cv[n], y);
                }
                y += __shfl_xor(y, 1, 64);
                if (!half) u_lb[l][d] = f2b_tr(fmaf(u_, dpd, y) * rsv);
            }
        }
        __syncthreads();

        // ---- G: xt += z[48,128] @ op[128,64] MFMA (LDS accumulate) -------
        {
            const int ntG = wave;
            for (int mt = 0; mt < 3; ++mt) {
                f32x4 c = {0.f, 0.f, 0.f, 0.f};
                #pragma unroll
                for (int kt = 0; kt < 4; ++kt) {
                    frag8 a  = *(const frag8*)&u_lb[mt * 16 + nl][kt * 32 + quad * 8];
                    frag8 bb = *(const frag8*)&op_b[((size_t)(sl * 64 + ntG * 16 + nl)) * 128 + kt * 32 + quad * 8];
                    c = __builtin_amdgcn_mfma_f32_16x16x32_bf16(a, bb, c, 0, 0, 0);
                }
                const int j = ntG * 16 + nl, r0 = mt * 16 + quad * 4;
                #pragma unroll
                for (int r = 0; r < 4; ++r) {
                    int row = r0 + r;
                    if (row < Lq) xt[row][j] += c[r];
                }
            }
        }
        __syncthreads();
    }

    // ---- write final residual to global ---------------------------------
    {
        float* xrow = X + ((size_t)(s * Bq + b)) * (Lq * Dq);
        const float* xf = &xt[0][0];
        for (int idx = tid; idx < Lq * Dq; idx += 256) xrow[idx] = xf[idx];
    }
}

// ---------------------------------------------------------------------------
// head_fuse: rmsnorm each (s,l) row, softmax-weighted stack sum -> Flat bf16
// ---------------------------------------------------------------------------
__global__ __launch_bounds__(256) void head_fuse(const float* __restrict__ X,
                                                 const float* __restrict__ norm_f_w,
                                                 const float* __restrict__ fusion_w,
                                                 unsigned short* __restrict__ Flat_b) {
    const int b    = blockIdx.x;
    const int tid  = threadIdx.x;
    const int wave = tid >> 6, lane = tid & 63;

    float fw0 = fusion_w[0], fw1 = fusion_w[1], fw2 = fusion_w[2];
    float m  = fmaxf(fw0, fmaxf(fw1, fw2));
    float e0 = __expf(fw0 - m), e1 = __expf(fw1 - m), e2 = __expf(fw2 - m);
    float inv = fast_rcp(e0 + e1 + e2);
    float w[NSq] = {e0 * inv, e1 * inv, e2 * inv};
    float nf = norm_f_w[lane];

    for (int l = wave; l < Lq; l += 4) {
        float acc = 0.f;
        #pragma unroll
        for (int s = 0; s < NSq; ++s) {
            float v  = X[(((size_t)s * Bq + b) * Lq + l) * Dq + lane];
            float ss = v * v;
            #pragma unroll
            for (int off = 32; off; off >>= 1) ss += __shfl_xor(ss, off, 64);
            acc += w[s] * v * __builtin_amdgcn_rsqf(ss * (1.0f / Dq) + 1e-5f);
        }
        Flat_b[(size_t)b * FLATq + l * Dq + lane] = f2b_tr(acc * nf);
    }
}

// ---------------------------------------------------------------------------
// head_tail: H1 = relu(Flat@W1+b1) via MFMA (frags straight from L2),
// then h2 = relu(H1@W2+b2), logit, sigmoid. One block per 16 batch rows.
// ---------------------------------------------------------------------------
__global__ __launch_bounds__(256) void head_tail(const unsigned short* __restrict__ Flat_b,
                                                 const unsigned short* __restrict__ W1b,
                                                 const float* __restrict__ b1,
                                                 const float* __restrict__ W2,
                                                 const float* __restrict__ b2,
                                                 const float* __restrict__ W3,
                                                 const float* __restrict__ b3,
                                                 float* __restrict__ out) {
    const int tid = threadIdx.x;
    const int wave = tid >> 6, lane = tid & 63;
    const int nl = lane & 15, quad = lane >> 4;
    const int b0 = blockIdx.x * 16;

    __shared__ float H1s[16][388];
    __shared__ float h2s[16][16];

    const unsigned short* Arow = Flat_b + (size_t)(b0 + nl) * FLATq + quad * 8;
    #pragma unroll
    for (int t = 0; t < 3; ++t) {
        const int ntA = wave + 4 * t, ntB = ntA + 12;
        const unsigned short* BrA = W1b + (size_t)(ntA * 16 + nl) * FLATq + quad * 8;
        const unsigned short* BrB = W1b + (size_t)(ntB * 16 + nl) * FLATq + quad * 8;
        f32x4 ca = {0.f,0.f,0.f,0.f}, cb = {0.f,0.f,0.f,0.f};
        for (int k0 = 0; k0 < FLATq; k0 += 32) {
            frag8 a  = *(const frag8*)(Arow + k0);
            frag8 ba = *(const frag8*)(BrA + k0);
            frag8 bbv = *(const frag8*)(BrB + k0);
            ca = __builtin_amdgcn_mfma_f32_16x16x32_bf16(a, ba, ca, 0, 0, 0);
            cb = __builtin_amdgcn_mfma_f32_16x16x32_bf16(a, bbv, cb, 0, 0, 0);
        }
        #pragma unroll
        for (int r = 0; r < 4; ++r) {
            int row = quad * 4 + r;
            int colA = ntA * 16 + nl, colB = ntB * 16 + nl;
            H1s[row][colA] = fmaxf(ca[r] + b1[colA], 0.f);
            H1s[row][colB] = fmaxf(cb[r] + b1[colB], 0.f);
        }
    }
    __syncthreads();
    {
        const int row = tid >> 4, g = tid & 15;
        float acc = b2[g];
        for (int k = 0; k < H1q; ++k) acc = fmaf(H1s[row][k], W2[k * H2q + g], acc);
        h2s[row][g] = fmaxf(acc, 0.f);
    }
    __syncthreads();
    if (tid < 16) {
        float z = b3[0];
        #pragma unroll
        for (int k = 0; k < H2q; ++k) z = fmaf(h2s[tid][k], W3[k], z);
        out[b0 + tid] = fast_rcp(1.f + __expf(-z));
    }
}

// ---------------------------------------------------------------------------
extern "C" void kernel_launch(void* const* d_in, const int* in_sizes, int n_in,
                              void* d_out, int out_size, void* d_ws, size_t ws_size,
                              hipStream_t stream) {
    const int*   ids      = (const int*)  d_in[0];
    const float* emb      = (const float*)d_in[1];
    const float* in_proj  = (const float*)d_in[2];
    const float* conv_w   = (const float*)d_in[3];
    const float* conv_b   = (const float*)d_in[4];
    const float* x_proj   = (const float*)d_in[5];
    const float* dt_w     = (const float*)d_in[6];
    const float* dt_b     = (const float*)d_in[7];
    const float* A_log    = (const float*)d_in[8];
    const float* Dp       = (const float*)d_in[9];
    const float* out_proj = (const float*)d_in[10];
    const float* norm_w   = (const float*)d_in[11];
    const float* norm_f_w = (const float*)d_in[12];
    const float* fusion_w = (const float*)d_in[13];
    const float* W1       = (const float*)d_in[14];
    const float* b1       = (const float*)d_in[15];
    const float* W2       = (const float*)d_in[16];
    const float* b2       = (const float*)d_in[17];
    const float* W3       = (const float*)d_in[18];
    const float* b3       = (const float*)d_in[19];
    float* out = (float*)d_out;

    // workspace: X fp32 4,030,464 f; then bf16 buffers
    float* X = (float*)d_ws;
    unsigned short* Flat_b = (unsigned short*)(X + (size_t)NSq*Bq*Lq*Dq);
    unsigned short* Wb_in  = Flat_b + (size_t)Bq*FLATq;
    unsigned short* xp_b   = Wb_in  + 9*256*64;
    unsigned short* op_b   = xp_b   + 9*48*128;
    unsigned short* W1b    = op_b   + 9*64*128;

    hipLaunchKernelGGL(prep_kernel, dim3(246 + 1080), dim3(256), 0, stream,
                       W1, in_proj, x_proj, out_proj, W1b, Wb_in, xp_b, op_b);

    hipLaunchKernelGGL(mamba_stack, dim3(Bq, NSq), dim3(256), 0, stream,
                       X, ids, emb, Wb_in, conv_w, conv_b, xp_b, dt_w, dt_b,
                       A_log, Dp, op_b, norm_w);

    hipLaunchKernelGGL(head_fuse, dim3(Bq), dim3(256), 0, stream,
                       X, norm_f_w, fusion_w, Flat_b);

    hipLaunchKernelGGL(head_tail, dim3(Bq/16), dim3(256), 0, stream,
                       Flat_b, W1b, b1, W2, b2, W3, b3, out);
}

// Round 5
// 310.858 us; speedup vs baseline: 1.2231x; 1.2231x over previous
//
#include <hip/hip_runtime.h>
#include <hip/hip_bf16.h>
#include <math.h>

// Problem constants
#define Bq  512
#define Lq  41
#define Vq  4
#define Dq  64
#define NLq 3
#define DIq 128
#define Nq  16
#define DTRq 4
#define Kq  4
#define NSq 3
#define H1q 384
#define H2q 16
#define FLATq (Lq*Dq)   // 2624

typedef __attribute__((ext_vector_type(8))) short frag8;   // 8 bf16 (4 VGPRs)
typedef __attribute__((ext_vector_type(4))) float f32x4;

__device__ __forceinline__ float b2f(unsigned short u) {
    union { float f; unsigned int i; } v; v.i = ((unsigned int)u) << 16; return v.f;
}
__device__ __forceinline__ unsigned short f2b_rne(float f) {
    union { float f; unsigned int i; } v; v.f = f;
    unsigned int x = v.i;
    return (unsigned short)((x + 0x7fffu + ((x >> 16) & 1u)) >> 16);
}
__device__ __forceinline__ unsigned short f2b_tr(float f) {
    union { float f; unsigned int i; } v; v.f = f;
    return (unsigned short)(v.i >> 16);
}
__device__ __forceinline__ float fast_rcp(float x) { return __builtin_amdgcn_rcpf(x); }

// ---------------------------------------------------------------------------
// prep: blocks [0,246) transpose W1 -> W1b bf16 [384][2624];
//       blocks [246,1326) convert/transpose small weights.
// ---------------------------------------------------------------------------
__global__ __launch_bounds__(256) void prep_kernel(const float* __restrict__ W1,
                                                   const float* __restrict__ in_proj,
                                                   const float* __restrict__ x_proj,
                                                   const float* __restrict__ out_proj,
                                                   unsigned short* __restrict__ W1b,
                                                   unsigned short* __restrict__ Wb_in,
                                                   unsigned short* __restrict__ xp_b,
                                                   unsigned short* __restrict__ op_b) {
    const int bx = blockIdx.x;
    if (bx < 246) {
        __shared__ float t[64][65];
        const int k0 = (bx / 6) * 64, n0 = (bx % 6) * 64;
        for (int idx = threadIdx.x; idx < 4096; idx += 256) {
            int kr = idx >> 6, nc = idx & 63;
            t[kr][nc] = W1[(size_t)(k0 + kr) * H1q + n0 + nc];
        }
        __syncthreads();
        for (int idx = threadIdx.x; idx < 4096; idx += 256) {
            int nr = idx >> 6, kc = idx & 63;
            W1b[(size_t)(n0 + nr) * FLATq + k0 + kc] = f2b_rne(t[kc][nr]);
        }
        return;
    }
    int idx = (bx - 246) * 256 + threadIdx.x;
    if (idx < 9*256*64) {
        int sl = idx >> 14, rem = idx & 16383;
        int n = rem >> 6, k = rem & 63;
        Wb_in[idx] = f2b_rne(in_proj[(size_t)sl*16384 + k*256 + n]);
    } else if (idx < 9*256*64 + 9*48*128) {
        int i2 = idx - 9*256*64;
        int sl = i2 / 6144, rem = i2 % 6144;
        int c = rem >> 7, k = rem & 127;
        float v = (c < 36) ? x_proj[(size_t)sl*(128*36) + k*36 + c] : 0.f;
        xp_b[i2] = f2b_rne(v);
    } else if (idx < 9*256*64 + 9*48*128 + 9*64*128) {
        int i3 = idx - (9*256*64 + 9*48*128);
        int sl = i3 >> 13, rem = i3 & 8191;
        int n = rem >> 7, k = rem & 127;
        op_b[i3] = f2b_rne(out_proj[(size_t)sl*8192 + k*64 + n]);
    }
}

// ---------------------------------------------------------------------------
// mamba_stack: ALL 3 layers for one (s,b), residual kept in LDS.
// Epilogue: fused final-rmsnorm + softmax(fusion_w) weighting ->
//   Xn[s][b][l][d] = sm[s] * rmsnorm(xt[l])[d] * norm_f_w[d]   (bf16)
// LDS: xt 10496 + u 13056 + rs 10496 + union{xn|dbl} 6912 = 40960 B -> 4 blk/CU
// ---------------------------------------------------------------------------
__global__ __launch_bounds__(256, 4) void mamba_stack(
    unsigned short* __restrict__ Xn,            // [NS][B][FLAT] bf16 OUTPUT
    const int* __restrict__ ids,
    const float* __restrict__ emb,
    const unsigned short* __restrict__ Wb_in,   // [9][256][64]
    const float* __restrict__ conv_w,
    const float* __restrict__ conv_b,
    const unsigned short* __restrict__ xp_b,    // [9][48][128]
    const float* __restrict__ dt_w,
    const float* __restrict__ dt_b,
    const float* __restrict__ A_log,
    const float* __restrict__ Dp,
    const unsigned short* __restrict__ op_b,    // [9][64][128]
    const float* __restrict__ norm_w,
    const float* __restrict__ norm_f_w,
    const float* __restrict__ fusion_w)
{
    const int b = blockIdx.x, s = blockIdx.y, tid = threadIdx.x;
    const int wave = tid >> 6, lane = tid & 63;
    const int nl = lane & 15, quad = lane >> 4;

    __shared__ float          xt  [Lq][64];     // residual stream (fp32)
    __shared__ unsigned short u_lb[48][136];    // bf16 u; z in place after scan
    __shared__ unsigned short rs_lb[Lq][128];   // bf16 silu(res)
    __shared__ __align__(16) char un_buf[6912]; // union: xn (A->B) | dbl (D->F)
    unsigned short (*xn_lb)[72] = (unsigned short(*)[72])un_buf;
    float          (*dbl_s)[40] = (float(*)[40])un_buf;

    // ---- residual init from embedding (layer 0) --------------------------
    for (int l = wave; l < Lq; l += 4) {
        int id = ids[b * Lq + l];
        xt[l][lane] = emb[id * Dq + lane];      // same (wave,lane) mapping as A
    }

    for (int layer = 0; layer < NLq; ++layer) {
        const int sl = s * NLq + layer;

        // ---- A: rmsnorm(xt) -> xn bf16; pad rows zeroed ------------------
        {
            const float nwv = norm_w[(size_t)sl * Dq + lane];
            for (int l = wave; l < 48; l += 4) {
                if (l < Lq) {
                    float v  = xt[l][lane];
                    float ss = v * v;
                    #pragma unroll
                    for (int off = 32; off; off >>= 1) ss += __shfl_xor(ss, off, 64);
                    float scale = __builtin_amdgcn_rsqf(ss * (1.0f / Dq) + 1e-5f);
                    xn_lb[l][lane] = f2b_tr(v * scale * nwv);
                } else {
                    xn_lb[l][lane] = 0;
                }
            }
        }
        __syncthreads();

        // ---- B: [48,64]@[64,256] MFMA -> u (cols<128), silu -> rs --------
        {
            #pragma unroll
            for (int t = 0; t < 12; ++t) {
                const int id = wave * 12 + t;
                const int mt = id >> 4, nt = id & 15;
                const unsigned short* Wp = Wb_in + ((size_t)(sl * 256 + nt * 16 + nl)) * 64 + quad * 8;
                frag8 a0 = *(const frag8*)&xn_lb[mt * 16 + nl][quad * 8];
                frag8 a1 = *(const frag8*)&xn_lb[mt * 16 + nl][32 + quad * 8];
                frag8 b0 = *(const frag8*)&Wp[0];
                frag8 b1 = *(const frag8*)&Wp[32];
                f32x4 c = {0.f, 0.f, 0.f, 0.f};
                c = __builtin_amdgcn_mfma_f32_16x16x32_bf16(a0, b0, c, 0, 0, 0);
                c = __builtin_amdgcn_mfma_f32_16x16x32_bf16(a1, b1, c, 0, 0, 0);
                const int col = nt * 16 + nl;
                const int r0 = mt * 16 + quad * 4;
                if (col < DIq) {
                    #pragma unroll
                    for (int r = 0; r < 4; ++r) u_lb[r0 + r][col] = f2b_tr(c[r]);
                } else {
                    const int d = col - DIq;
                    #pragma unroll
                    for (int r = 0; r < 4; ++r) {
                        int row = r0 + r;
                        if (row < Lq) {
                            float v = c[r];
                            rs_lb[row][d] = f2b_tr(v * fast_rcp(1.f + __expf(-v)));
                        }
                    }
                }
            }
        }
        __syncthreads();

        // ---- C: depthwise causal conv (K=4) + bias + silu, in place ------
        {
            const float* cw = conv_w + (size_t)sl * (DIq * Kq);
            const int d = tid >> 1, half = tid & 1;
            const float c0 = cw[d*4+0], c1 = cw[d*4+1], c2 = cw[d*4+2], c3 = cw[d*4+3];
            const float cbv = conv_b[(size_t)sl * DIq + d];
            float w0 = 0.f, w1 = 0.f, w2 = 0.f;
            if (half) { w0 = b2f(u_lb[18][d]); w1 = b2f(u_lb[19][d]); w2 = b2f(u_lb[20][d]); }
            const int base = half ? 21 : 0;
            const int cnt  = half ? 20 : 21;
            for (int i = 0; i < cnt; ++i) {
                int l = base + i;
                float cur = b2f(u_lb[l][d]);
                float a = fmaf(w0, c0, fmaf(w1, c1, fmaf(w2, c2, fmaf(cur, c3, cbv))));
                u_lb[l][d] = f2b_tr(a * fast_rcp(1.f + __expf(-a)));
                w0 = w1; w1 = w2; w2 = cur;
            }
        }
        __syncthreads();

        // ---- D: dbl = u[48,128] @ xp[128,48] MFMA (keep cols<40) ---------
        {
            for (int t = wave; t < 9; t += 4) {
                const int mt = t / 3, ct = t % 3;
                f32x4 c = {0.f, 0.f, 0.f, 0.f};
                #pragma unroll
                for (int kt = 0; kt < 4; ++kt) {
                    frag8 a  = *(const frag8*)&u_lb[mt * 16 + nl][kt * 32 + quad * 8];
                    frag8 bb = *(const frag8*)&xp_b[((size_t)(sl * 48 + ct * 16 + nl)) * 128 + kt * 32 + quad * 8];
                    c = __builtin_amdgcn_mfma_f32_16x16x32_bf16(a, bb, c, 0, 0, 0);
                }
                const int col = ct * 16 + nl, r0 = mt * 16 + quad * 4;
                if (col < 40) {
                    #pragma unroll
                    for (int r = 0; r < 4; ++r) {
                        int row = r0 + r;
                        if (row < Lq) dbl_s[row][col] = c[r];
                    }
                }
            }
        }
        __syncthreads();

        // ---- F: selective scan, fp32 state; z -> u_lb in place -----------
        {
            const int d = tid >> 1, half = tid & 1;
            const float* al = A_log + (size_t)sl * (DIq * Nq) + d * Nq + half * 8;
            float A2[8], h[8];
            #pragma unroll
            for (int n = 0; n < 8; ++n) {
                A2[n] = -__expf(al[n]) * 1.442695041f;   // fold log2(e) into A
                h[n] = 0.f;
            }
            const float* dw = dt_w + (size_t)sl * (DTRq * DIq);
            const float dw0 = dw[d], dw1 = dw[DIq + d], dw2 = dw[2*DIq + d], dw3 = dw[3*DIq + d];
            const float dbv = dt_b[(size_t)sl * DIq + d];
            const float dpd = Dp[(size_t)sl * DIq + d];
            for (int l = 0; l < Lq; ++l) {
                float4 q0 = *(const float4*)&dbl_s[l][0];
                float x  = fmaf(q0.x, dw0, fmaf(q0.y, dw1, fmaf(q0.z, dw2, fmaf(q0.w, dw3, dbv))));
                float dt_ = fmaxf(x, 0.f) + __logf(1.f + __expf(-fabsf(x)));
                float u_  = b2f(u_lb[l][d]);
                float rsv = b2f(rs_lb[l][d]);
                float4 B0 = *(const float4*)&dbl_s[l][4  + half * 8];
                float4 B1 = *(const float4*)&dbl_s[l][8  + half * 8];
                float4 C0 = *(const float4*)&dbl_s[l][20 + half * 8];
                float4 C1 = *(const float4*)&dbl_s[l][24 + half * 8];
                float dtu = dt_ * u_;
                float Bv[8] = {B0.x,B0.y,B0.z,B0.w,B1.x,B1.y,B1.z,B1.w};
                float Cv[8] = {C0.x,C0.y,C0.z,C0.w,C1.x,C1.y,C1.z,C1.w};
                float y = 0.f;
                #pragma unroll
                for (int n = 0; n < 8; ++n) {
                    float dA = __builtin_amdgcn_exp2f(dt_ * A2[n]);
                    h[n] = fmaf(dA, h[n], Bv[n] * dtu);
                    y    = fmaf(h[n], Cv[n], y);
                }
                y += __shfl_xor(y, 1, 64);
                if (!half) u_lb[l][d] = f2b_tr(fmaf(u_, dpd, y) * rsv);
            }
        }
        __syncthreads();

        // ---- G: xt += z[48,128] @ op[128,64] MFMA (LDS accumulate) -------
        {
            const int ntG = wave;
            for (int mt = 0; mt < 3; ++mt) {
                f32x4 c = {0.f, 0.f, 0.f, 0.f};
                #pragma unroll
                for (int kt = 0; kt < 4; ++kt) {
                    frag8 a  = *(const frag8*)&u_lb[mt * 16 + nl][kt * 32 + quad * 8];
                    frag8 bb = *(const frag8*)&op_b[((size_t)(sl * 64 + ntG * 16 + nl)) * 128 + kt * 32 + quad * 8];
                    c = __builtin_amdgcn_mfma_f32_16x16x32_bf16(a, bb, c, 0, 0, 0);
                }
                const int j = ntG * 16 + nl, r0 = mt * 16 + quad * 4;
                #pragma unroll
                for (int r = 0; r < 4; ++r) {
                    int row = r0 + r;
                    if (row < Lq) xt[row][j] += c[r];
                }
            }
        }
        __syncthreads();
    }

    // ---- Epilogue: fused final rmsnorm + fusion weighting -> Xn bf16 -----
    {
        float fw0 = fusion_w[0], fw1 = fusion_w[1], fw2 = fusion_w[2];
        float mx = fmaxf(fw0, fmaxf(fw1, fw2));
        float e0 = __expf(fw0 - mx), e1 = __expf(fw1 - mx), e2 = __expf(fw2 - mx);
        float sw = (s == 0 ? e0 : (s == 1 ? e1 : e2)) * fast_rcp(e0 + e1 + e2);
        float nf = norm_f_w[lane] * sw;
        unsigned short* xr = Xn + ((size_t)s * Bq + b) * FLATq;
        for (int l = wave; l < Lq; l += 4) {
            float v  = xt[l][lane];
            float ss = v * v;
            #pragma unroll
            for (int off = 32; off; off >>= 1) ss += __shfl_xor(ss, off, 64);
            float scale = __builtin_amdgcn_rsqf(ss * (1.0f / Dq) + 1e-5f);
            xr[l * Dq + lane] = f2b_tr(v * scale * nf);
        }
    }
}

// ---------------------------------------------------------------------------
// head_gemm1: H1 = relu( (Σ_s Xn_s) @ W1 + b1 ) via 3 accumulated MFMA
// chains (linearity — sm[s] already folded into Xn). grid (32 mt, 6 nt);
// 4 waves split K (21/21/20/20 of 82 steps); LDS reduce; fused bias+relu.
// ---------------------------------------------------------------------------
__global__ __launch_bounds__(256) void head_gemm1(const unsigned short* __restrict__ Xn,
                                                  const unsigned short* __restrict__ W1b,
                                                  const float* __restrict__ b1,
                                                  float* __restrict__ H1) {
    const int tid = threadIdx.x;
    const int wave = tid >> 6, lane = tid & 63;
    const int nl = lane & 15, quad = lane >> 4;
    const int mt = blockIdx.x, nt = blockIdx.y;

    __shared__ float red[4][16][17];

    const int kbeg = (wave < 2) ? wave * 21 : 42 + (wave - 2) * 20;
    const int kcnt = (wave < 2) ? 21 : 20;
    const size_t SB = (size_t)Bq * FLATq;
    const unsigned short* A0 = Xn  + (size_t)(mt * 16 + nl) * FLATq + quad * 8;
    const unsigned short* Br = W1b + (size_t)(nt * 16 + nl) * FLATq + quad * 8;

    f32x4 c = {0.f, 0.f, 0.f, 0.f};
    for (int ks = kbeg; ks < kbeg + kcnt; ++ks) {
        const int off = ks * 32;
        frag8 bb = *(const frag8*)(Br + off);
        frag8 a0 = *(const frag8*)(A0 + off);
        frag8 a1 = *(const frag8*)(A0 + SB + off);
        frag8 a2 = *(const frag8*)(A0 + 2 * SB + off);
        c = __builtin_amdgcn_mfma_f32_16x16x32_bf16(a0, bb, c, 0, 0, 0);
        c = __builtin_amdgcn_mfma_f32_16x16x32_bf16(a1, bb, c, 0, 0, 0);
        c = __builtin_amdgcn_mfma_f32_16x16x32_bf16(a2, bb, c, 0, 0, 0);
    }
    #pragma unroll
    for (int r = 0; r < 4; ++r) red[wave][quad * 4 + r][nl] = c[r];
    __syncthreads();

    const int row = tid >> 4, colv = tid & 15;
    float acc = red[0][row][colv] + red[1][row][colv]
              + red[2][row][colv] + red[3][row][colv];
    const int col = nt * 16 + colv;
    H1[(size_t)(mt * 16 + row) * H1q + col] = fmaxf(acc + b1[col], 0.f);
}

// ---------------------------------------------------------------------------
// head_final: h2 = relu(H1@W2+b2); out = sigmoid(h2@W3+b3). 16 batches/block.
// ---------------------------------------------------------------------------
__global__ __launch_bounds__(256) void head_final(const float* __restrict__ H1,
                                                  const float* __restrict__ W2,
                                                  const float* __restrict__ b2,
                                                  const float* __restrict__ W3,
                                                  const float* __restrict__ b3,
                                                  float* __restrict__ out) {
    const int b0 = blockIdx.x * 16, tid = threadIdx.x;
    __shared__ float H1s[16 * H1q];
    __shared__ float h2s[16][16];
    for (int idx = tid; idx < 16 * H1q; idx += 256)
        H1s[idx] = H1[(size_t)b0 * H1q + idx];
    __syncthreads();
    {
        const int row = tid >> 4, g = tid & 15;
        float acc = b2[g];
        for (int k = 0; k < H1q; ++k)
            acc = fmaf(H1s[row * H1q + k], W2[k * H2q + g], acc);
        h2s[row][g] = fmaxf(acc, 0.f);
    }
    __syncthreads();
    if (tid < 16) {
        float z = b3[0];
        #pragma unroll
        for (int k = 0; k < H2q; ++k) z = fmaf(h2s[tid][k], W3[k], z);
        out[b0 + tid] = fast_rcp(1.f + __expf(-z));
    }
}

// ---------------------------------------------------------------------------
extern "C" void kernel_launch(void* const* d_in, const int* in_sizes, int n_in,
                              void* d_out, int out_size, void* d_ws, size_t ws_size,
                              hipStream_t stream) {
    const int*   ids      = (const int*)  d_in[0];
    const float* emb      = (const float*)d_in[1];
    const float* in_proj  = (const float*)d_in[2];
    const float* conv_w   = (const float*)d_in[3];
    const float* conv_b   = (const float*)d_in[4];
    const float* x_proj   = (const float*)d_in[5];
    const float* dt_w     = (const float*)d_in[6];
    const float* dt_b     = (const float*)d_in[7];
    const float* A_log    = (const float*)d_in[8];
    const float* Dp       = (const float*)d_in[9];
    const float* out_proj = (const float*)d_in[10];
    const float* norm_w   = (const float*)d_in[11];
    const float* norm_f_w = (const float*)d_in[12];
    const float* fusion_w = (const float*)d_in[13];
    const float* W1       = (const float*)d_in[14];
    const float* b1       = (const float*)d_in[15];
    const float* W2       = (const float*)d_in[16];
    const float* b2       = (const float*)d_in[17];
    const float* W3       = (const float*)d_in[18];
    const float* b3       = (const float*)d_in[19];
    float* out = (float*)d_out;

    // workspace (shorts unless noted):
    //   Xn    3*512*2624 = 4,030,464
    //   Wb_in   147,456 | xp_b 55,296 | op_b 73,728 | W1b 1,007,616
    //   H1 (fp32) 512*384 = 196,608 floats
    unsigned short* Xn    = (unsigned short*)d_ws;
    unsigned short* Wb_in = Xn    + (size_t)NSq * Bq * FLATq;
    unsigned short* xp_b  = Wb_in + 9*256*64;
    unsigned short* op_b  = xp_b  + 9*48*128;
    unsigned short* W1b   = op_b  + 9*64*128;
    float*          H1    = (float*)(W1b + (size_t)H1q * FLATq);

    hipLaunchKernelGGL(prep_kernel, dim3(246 + 1080), dim3(256), 0, stream,
                       W1, in_proj, x_proj, out_proj, W1b, Wb_in, xp_b, op_b);

    hipLaunchKernelGGL(mamba_stack, dim3(Bq, NSq), dim3(256), 0, stream,
                       Xn, ids, emb, Wb_in, conv_w, conv_b, xp_b, dt_w, dt_b,
                       A_log, Dp, op_b, norm_w, norm_f_w, fusion_w);

    hipLaunchKernelGGL(head_gemm1, dim3(Bq/16, H1q/64), dim3(256), 0, stream,
                       Xn, W1b, b1, H1);

    hipLaunchKernelGGL(head_final, dim3(Bq/16), dim3(256), 0, stream,
                       H1, W2, b2, W3, b3, out);
}